// Round 6
// baseline (164.462 us; speedup 1.0000x reference)
//
#include <hip/hip_runtime.h>
#include <stdint.h>

#define NH 8
#define D 8
#define HH 48
#define WW 48
#define NQ (HH*WW)          // 2304
#define BB 2
#define NBH (BB*NH)         // 16
#define NQG (NBH*NQ)        // 36864 queries total
#define NGT 576             // wave-tiles of 64 queries
#define SCL 0.51011868f     // 8^-0.5 * log2(e)  (folded so softmax = exp2)
#define SHIFT 17.312340491f // 12 * log2(e)      (fixed-shift softmax)

typedef __attribute__((ext_vector_type(8))) float f8;

// ---------------------------------------------------------------------------
// attn: lane = query (256 distinct queries / block). KV rows are wave-uniform
// -> fetched with s_load_dwordx8 into SGPRs (inline asm); every K/V element
// is consumed as the SGPR operand of a VALU fma: zero per-lane delivery cost
// (LDS/VMEM broadcast pays ~1KB register-file return per instr - R5's wall).
// SMEM completes out-of-order so only lgkmcnt(0) is reliable: batch 3 keys,
// wait(0), compute; wave TLP hides the per-batch latency.
// logit = q.k + q.rel_w[x2-x+47] + q.rel_h[y2-y+47]; p = exp2(logit' - SHIFT)
// ---------------------------------------------------------------------------
template<int ROWS>
__global__ __launch_bounds__(256) void attn_kernel(const float* __restrict__ in,
                                                   const float* __restrict__ relw,
                                                   const float* __restrict__ relh,
                                                   float* __restrict__ P) {
    constexpr int NCH = 48 / ROWS;          // number of key chunks

    const int bx = blockIdx.x;
    const int bh = bx / (9 * NCH);
    const int rem = bx % (9 * NCH);
    const int qt = rem / NCH;
    const int kc = rem % NCH;
    const int tid = threadIdx.x;
    const int lane = tid & 63;
    const int wv = tid >> 6;
    const int b = bh >> 3, h = bh & 7;

    const float4* inp4 = (const float4*)in;   // 48 float4 per pixel (C=192)

    // ---- per-lane query (scaled by 8^-0.5 * log2e) ----
    const int n = qt * 256 + wv * 64 + lane;
    const int y = n / WW, x = n - y * WW;
    float4 qa = inp4[(size_t)(b * NQ + n) * 48 + h * 2];
    float4 qb = inp4[(size_t)(b * NQ + n) * 48 + h * 2 + 1];
    qa.x *= SCL; qa.y *= SCL; qa.z *= SCL; qa.w *= SCL;
    qb.x *= SCL; qb.y *= SCL; qb.z *= SCL; qb.w *= SCL;

    // qw[x2] = q . rel_w[x2 - x + 47]  (static indices -> stays in VGPRs)
    float qw[48];
#pragma unroll
    for (int x2 = 0; x2 < 48; ++x2) {
        const float* rw = relw + (x2 - x + 47) * 8;
        float4 ta = *(const float4*)rw;
        float4 tb = *(const float4*)(rw + 4);
        qw[x2] = qa.x * ta.x + qa.y * ta.y + qa.z * ta.z + qa.w * ta.w
               + qb.x * tb.x + qb.y * tb.y + qb.z * tb.z + qb.w * tb.w;
    }

    float l = 0.0f;
    float a0 = 0, a1 = 0, a2 = 0, a3 = 0, a4 = 0, a5 = 0, a6 = 0, a7 = 0;

    // scalar byte offsets of K (and V at +256B) for first key of the chunk
    int koff = ((b * NQ + kc * (ROWS * 48)) * 192 + 64 + h * 8) * 4;
    int voff = koff + 256;

#pragma unroll 1
    for (int rr = 0; rr < ROWS; ++rr) {
        const int r = kc * ROWS + rr;       // key row y2
        const float* rh = relh + (r - y + 47) * 8;   // <=2 lines per wave
        float4 ha = *(const float4*)rh;
        float4 hb = *(const float4*)(rh + 4);
        float qh = qa.x * ha.x + qa.y * ha.y + qa.z * ha.z + qa.w * ha.w
                 + qb.x * hb.x + qb.y * hb.y + qb.z * hb.z + qb.w * hb.w
                 - SHIFT;

#pragma unroll
        for (int bt = 0; bt < 16; ++bt) {
            f8 k0, k1, k2, v0, v1, v2;
            asm volatile("s_load_dwordx8 %0, %1, %2" : "=&s"(k0) : "s"(in), "s"(koff));
            asm volatile("s_load_dwordx8 %0, %1, %2" : "=&s"(v0) : "s"(in), "s"(voff));
            koff += 768; voff += 768;
            asm volatile("s_load_dwordx8 %0, %1, %2" : "=&s"(k1) : "s"(in), "s"(koff));
            asm volatile("s_load_dwordx8 %0, %1, %2" : "=&s"(v1) : "s"(in), "s"(voff));
            koff += 768; voff += 768;
            asm volatile("s_load_dwordx8 %0, %1, %2" : "=&s"(k2) : "s"(in), "s"(koff));
            asm volatile("s_load_dwordx8 %0, %1, %2" : "=&s"(v2) : "s"(in), "s"(voff));
            koff += 768; voff += 768;
            asm volatile("s_waitcnt lgkmcnt(0)"
                         : "+s"(k0), "+s"(k1), "+s"(k2),
                           "+s"(v0), "+s"(v1), "+s"(v2));
#pragma unroll
            for (int i = 0; i < 3; ++i) {
                const f8 kk = (i == 0) ? k0 : (i == 1) ? k1 : k2;
                const f8 vv = (i == 0) ? v0 : (i == 1) ? v1 : v2;
                const int x2 = bt * 3 + i;
                float dt = qh + qw[x2];
                dt = fmaf(qa.x, kk[0], dt); dt = fmaf(qa.y, kk[1], dt);
                dt = fmaf(qa.z, kk[2], dt); dt = fmaf(qa.w, kk[3], dt);
                dt = fmaf(qb.x, kk[4], dt); dt = fmaf(qb.y, kk[5], dt);
                dt = fmaf(qb.z, kk[6], dt); dt = fmaf(qb.w, kk[7], dt);
                float p = __builtin_amdgcn_exp2f(dt);
                l += p;
                a0 = fmaf(p, vv[0], a0); a1 = fmaf(p, vv[1], a1);
                a2 = fmaf(p, vv[2], a2); a3 = fmaf(p, vv[3], a3);
                a4 = fmaf(p, vv[4], a4); a5 = fmaf(p, vv[5], a5);
                a6 = fmaf(p, vv[6], a6); a7 = fmaf(p, vv[7], a7);
            }
        }
    }

    // ---- write partials, coalesced: slab = (kc*NGT + g), layout [9][64] ----
    const int g = (bh * 9 + qt) * 4 + wv;   // wave-tile id [0, 576)
    float* pb = P + (size_t)(kc * NGT + g) * 576;
    pb[0 * 64 + lane] = l;
    pb[1 * 64 + lane] = a0; pb[2 * 64 + lane] = a1;
    pb[3 * 64 + lane] = a2; pb[4 * 64 + lane] = a3;
    pb[5 * 64 + lane] = a4; pb[6 * 64 + lane] = a5;
    pb[7 * 64 + lane] = a6; pb[8 * 64 + lane] = a7;
}

// ---------------------------------------------------------------------------
// merge: sum nch partials per query, normalize, write out[b][n][h*8+j]
// ---------------------------------------------------------------------------
__global__ __launch_bounds__(256) void merge_kernel(const float* __restrict__ P,
                                                    float* __restrict__ out,
                                                    int nch) {
    const int t = blockIdx.x * blockDim.x + threadIdx.x;  // [0, NQG)
    const int g = t >> 6, lane = t & 63;
    float s[9];
#pragma unroll
    for (int j = 0; j < 9; ++j) s[j] = 0.0f;
    for (int c = 0; c < nch; ++c) {
        const float* pb = P + (size_t)(c * NGT + g) * 576;
#pragma unroll
        for (int j = 0; j < 9; ++j) s[j] += pb[j * 64 + lane];
    }
    float inv = 1.0f / s[0];
    const int bh = g / 36;
    const int r = g % 36;
    const int n = (r >> 2) * 256 + (r & 3) * 64 + lane;
    const int b = bh >> 3, h = bh & 7;
    float* op = out + ((size_t)(b * NQ + n) * 64 + h * 8);
    float4 o0 = make_float4(s[1] * inv, s[2] * inv, s[3] * inv, s[4] * inv);
    float4 o1 = make_float4(s[5] * inv, s[6] * inv, s[7] * inv, s[8] * inv);
    ((float4*)op)[0] = o0;
    ((float4*)op)[1] = o1;
}

extern "C" void kernel_launch(void* const* d_in, const int* in_sizes, int n_in,
                              void* d_out, int out_size, void* d_ws, size_t ws_size,
                              hipStream_t stream) {
    const float* in   = (const float*)d_in[0];
    const float* relw = (const float*)d_in[1];
    const float* relh = (const float*)d_in[2];
    float* P   = (float*)d_ws;
    float* out = (float*)d_out;

    // P needs nch * NGT * 576 floats; pick key-split by ws budget
    const size_t need8 = (size_t)8 * NGT * 576 * 4;
    if (ws_size >= need8) {
        attn_kernel<6><<<NBH * 9 * 8, 256, 0, stream>>>(in, relw, relh, P);
        merge_kernel<<<NQG / 256, 256, 0, stream>>>(P, out, 8);
    } else {
        attn_kernel<12><<<NBH * 9 * 4, 256, 0, stream>>>(in, relw, relh, P);
        merge_kernel<<<NQG / 256, 256, 0, stream>>>(P, out, 4);
    }
}